// Round 1
// baseline (466.139 us; speedup 1.0000x reference)
//
#include <hip/hip_runtime.h>
#include <math.h>

// ---------------------------------------------------------------------------
// LearnableDCTNet: per-8x8-block DCT -> learned mask -> IDCT, low/high split.
//   low  = C^T ((C X C^T) * Q) C
//   high = X - low            (C orthonormal to ~2e-7; threshold is 1.08e-1)
// C is a compile-time constant (exact DCT-II basis; reference's truncated-pi
// basis differs by <2e-7 per entry -> ~1e-5 at output).
// Q (8x8) comes from the tiny noise MLP, computed by a 64-thread setup kernel
// in fp64 into d_ws.
// ---------------------------------------------------------------------------

// cos(k*pi/16), k = 0..31 (full period)
__host__ __device__ constexpr float cc(int i, int j) {
  constexpr double COS16[32] = {
     1.0,
     0.98078528040323043,
     0.92387953251128674,
     0.83146961230254524,
     0.70710678118654752,
     0.55557023301960222,
     0.38268343236508977,
     0.19509032201612827,
     0.0,
    -0.19509032201612827,
    -0.38268343236508977,
    -0.55557023301960222,
    -0.70710678118654752,
    -0.83146961230254524,
    -0.92387953251128674,
    -0.98078528040323043,
    -1.0,
    -0.98078528040323043,
    -0.92387953251128674,
    -0.83146961230254524,
    -0.70710678118654752,
    -0.55557023301960222,
    -0.38268343236508977,
    -0.19509032201612827,
     0.0,
     0.19509032201612827,
     0.38268343236508977,
     0.55557023301960222,
     0.70710678118654752,
     0.83146961230254524,
     0.92387953251128674,
     0.98078528040323043,
  };
  // C[0][j] = sqrt(1/8); C[i][j] = sqrt(2/8) * cos(pi*i*(2j+1)/16), sqrt(2/8)=0.5
  return (i == 0) ? 0.35355339059327373f
                  : (float)(0.5 * COS16[(i * (2 * j + 1)) % 32]);
}

// ---------------------------------------------------------------------------
// Setup: noise MLP (exact-erf GELU) -> nr[18]; softmax(qmat_weights);
// coeff[i] = (softmax_i*nr[0] + nr[1]) * nr[2+i]; Q = sum_i coeff[i]*qmat[i].
// 64 floats written to qout (d_ws).
// ---------------------------------------------------------------------------
__global__ void setup_q(const float* __restrict__ noise,
                        const float* __restrict__ qmat,
                        const float* __restrict__ qmw,
                        const float* __restrict__ w1, const float* __restrict__ b1,
                        const float* __restrict__ w2, const float* __restrict__ b2,
                        const float* __restrict__ w3, const float* __restrict__ b3,
                        float* __restrict__ qout) {
  __shared__ double coeff[16];
  if (threadIdx.x == 0) {
    const double inv_sqrt2 = 0.70710678118654752;
    double h1[16], h2[16], nr[18];
    double nl = (double)noise[0];
    for (int j = 0; j < 16; ++j) {
      double v = nl * (double)w1[j] + (double)b1[j];
      h1[j] = 0.5 * v * (1.0 + erf(v * inv_sqrt2));
    }
    for (int j = 0; j < 16; ++j) {
      double v = (double)b2[j];
      for (int i = 0; i < 16; ++i) v += h1[i] * (double)w2[i * 16 + j];
      h2[j] = 0.5 * v * (1.0 + erf(v * inv_sqrt2));
    }
    for (int j = 0; j < 18; ++j) {
      double v = (double)b3[j];
      for (int i = 0; i < 16; ++i) v += h2[i] * (double)w3[i * 18 + j];
      nr[j] = v;
    }
    double mx = (double)qmw[0];
    for (int i = 1; i < 16; ++i) mx = fmax(mx, (double)qmw[i]);
    double e[16], s = 0.0;
    for (int i = 0; i < 16; ++i) { e[i] = exp((double)qmw[i] - mx); s += e[i]; }
    for (int i = 0; i < 16; ++i)
      coeff[i] = (e[i] / s * nr[0] + nr[1]) * nr[2 + i];
  }
  __syncthreads();
  const int t = threadIdx.x;  // 64 threads, one Q entry each
  double q = 0.0;
  for (int i = 0; i < 16; ++i) q += coeff[i] * (double)qmat[i * 64 + t];
  qout[t] = (float)q;
}

// ---------------------------------------------------------------------------
// Main: one thread per 8x8 block. X kept in 64 regs for high = X - low.
// All loops fully unrolled; C folds to literals (zero register cost).
// ---------------------------------------------------------------------------
__global__ __launch_bounds__(256) void dct_main(const float* __restrict__ x,
                                                const float* __restrict__ qb,
                                                float* __restrict__ lo,
                                                float* __restrict__ hi) {
  const int gid = blockIdx.x * 256 + threadIdx.x;
  // image n = gid>>6, band = (gid>>3)&7, block-col = gid&7 ; W = 64 floats/row
  const int base = ((gid >> 6) << 12) | (((gid >> 3) & 7) << 9) | ((gid & 7) << 3);
  const float* px = x + base;

  float X[8][8];
#pragma unroll
  for (int r = 0; r < 8; ++r) {
    const float4 a = *reinterpret_cast<const float4*>(px + r * 64);
    const float4 b = *reinterpret_cast<const float4*>(px + r * 64 + 4);
    X[r][0] = a.x; X[r][1] = a.y; X[r][2] = a.z; X[r][3] = a.w;
    X[r][4] = b.x; X[r][5] = b.y; X[r][6] = b.z; X[r][7] = b.w;
  }

  float U[8][8];
  // Stage 1: U = X * C^T   (U[r][j] = sum_l X[r][l] * C[j][l])
#pragma unroll
  for (int r = 0; r < 8; ++r) {
#pragma unroll
    for (int j = 0; j < 8; ++j) {
      float s = X[r][0] * cc(j, 0);
#pragma unroll
      for (int l = 1; l < 8; ++l) s = fmaf(X[r][l], cc(j, l), s);
      U[r][j] = s;
    }
  }
  // Stage 2: D = C * U, fused mask: U[i][j] = D[i][j] * Q[i][j]
#pragma unroll
  for (int j = 0; j < 8; ++j) {
    float t[8];
#pragma unroll
    for (int i = 0; i < 8; ++i) {
      float s = cc(i, 0) * U[0][j];
#pragma unroll
      for (int k = 1; k < 8; ++k) s = fmaf(cc(i, k), U[k][j], s);
      t[i] = s;
    }
#pragma unroll
    for (int i = 0; i < 8; ++i) U[i][j] = t[i] * qb[i * 8 + j];
  }
  // Stage 3: V = M * C   (V[r][j] = sum_k M[r][k] * C[k][j])
#pragma unroll
  for (int r = 0; r < 8; ++r) {
    float t[8];
#pragma unroll
    for (int j = 0; j < 8; ++j) {
      float s = U[r][0] * cc(0, j);
#pragma unroll
      for (int k = 1; k < 8; ++k) s = fmaf(U[r][k], cc(k, j), s);
      t[j] = s;
    }
#pragma unroll
    for (int j = 0; j < 8; ++j) U[r][j] = t[j];
  }
  // Stage 4: low = C^T * V   (low[i][j] = sum_k C[k][i] * V[k][j])
#pragma unroll
  for (int j = 0; j < 8; ++j) {
    float t[8];
#pragma unroll
    for (int i = 0; i < 8; ++i) {
      float s = cc(0, i) * U[0][j];
#pragma unroll
      for (int k = 1; k < 8; ++k) s = fmaf(cc(k, i), U[k][j], s);
      t[i] = s;
    }
#pragma unroll
    for (int i = 0; i < 8; ++i) U[i][j] = t[i];
  }

  float* plo = lo + base;
  float* phi = hi + base;
#pragma unroll
  for (int r = 0; r < 8; ++r) {
    float4 a = make_float4(U[r][0], U[r][1], U[r][2], U[r][3]);
    float4 b = make_float4(U[r][4], U[r][5], U[r][6], U[r][7]);
    *reinterpret_cast<float4*>(plo + r * 64)     = a;
    *reinterpret_cast<float4*>(plo + r * 64 + 4) = b;
    float4 c = make_float4(X[r][0] - U[r][0], X[r][1] - U[r][1],
                           X[r][2] - U[r][2], X[r][3] - U[r][3]);
    float4 d = make_float4(X[r][4] - U[r][4], X[r][5] - U[r][5],
                           X[r][6] - U[r][6], X[r][7] - U[r][7]);
    *reinterpret_cast<float4*>(phi + r * 64)     = c;
    *reinterpret_cast<float4*>(phi + r * 64 + 4) = d;
  }
}

extern "C" void kernel_launch(void* const* d_in, const int* in_sizes, int n_in,
                              void* d_out, int out_size, void* d_ws, size_t ws_size,
                              hipStream_t stream) {
  const float* x   = (const float*)d_in[0];
  const float* nl  = (const float*)d_in[1];
  const float* qm  = (const float*)d_in[2];
  const float* qmw = (const float*)d_in[3];
  const float* w1  = (const float*)d_in[4];
  const float* b1  = (const float*)d_in[5];
  const float* w2  = (const float*)d_in[6];
  const float* b2  = (const float*)d_in[7];
  const float* w3  = (const float*)d_in[8];
  const float* b3  = (const float*)d_in[9];

  const int n_elem = in_sizes[0];          // 33554432
  float* lo = (float*)d_out;
  float* hi = lo + n_elem;
  float* q  = (float*)d_ws;                // 64 floats

  setup_q<<<1, 64, 0, stream>>>(nl, qm, qmw, w1, b1, w2, b2, w3, b3, q);

  const int n_blocks8 = n_elem >> 6;       // 524288 8x8 blocks
  const int grid = n_blocks8 >> 8;         // 2048 workgroups of 256
  dct_main<<<grid, 256, 0, stream>>>(x, q, lo, hi);
}

// Round 2
// 448.107 us; speedup vs baseline: 1.0402x; 1.0402x over previous
//
#include <hip/hip_runtime.h>
#include <math.h>

// ---------------------------------------------------------------------------
// LearnableDCTNet, fully fused single kernel.
//   low  = C^T ((C X C^T) * Q) C ;  high = X - low
// C is a compile-time constant (exact DCT-II basis; reference's truncated-pi
// basis differs by <2e-7/entry -> ~1e-5 at output; threshold 1.08e-1).
// Q (8x8) from the tiny noise MLP is recomputed per-workgroup in fp32 into
// LDS (parallel over 16 lanes; ~1-2 us overlapped) -- removes the separate
// setup kernel launch + inter-kernel dependency.
// x / lo / hi are use-once streams -> nontemporal loads/stores.
// ---------------------------------------------------------------------------

typedef float f4 __attribute__((ext_vector_type(4)));

// cos(k*pi/16), k = 0..31 (full period)
__host__ __device__ constexpr float cc(int i, int j) {
  constexpr double COS16[32] = {
     1.0,
     0.98078528040323043,
     0.92387953251128674,
     0.83146961230254524,
     0.70710678118654752,
     0.55557023301960222,
     0.38268343236508977,
     0.19509032201612827,
     0.0,
    -0.19509032201612827,
    -0.38268343236508977,
    -0.55557023301960222,
    -0.70710678118654752,
    -0.83146961230254524,
    -0.92387953251128674,
    -0.98078528040323043,
    -1.0,
    -0.98078528040323043,
    -0.92387953251128674,
    -0.83146961230254524,
    -0.70710678118654752,
    -0.55557023301960222,
    -0.38268343236508977,
    -0.19509032201612827,
     0.0,
     0.19509032201612827,
     0.38268343236508977,
     0.55557023301960222,
     0.70710678118654752,
     0.83146961230254524,
     0.92387953251128674,
     0.98078528040323043,
  };
  // C[0][j] = sqrt(1/8); C[i][j] = 0.5 * cos(pi*i*(2j+1)/16)
  return (i == 0) ? 0.35355339059327373f
                  : (float)(0.5 * COS16[(i * (2 * j + 1)) % 32]);
}

__device__ __forceinline__ float gelu_exact(float v) {
  return 0.5f * v * (1.0f + erff(v * 0.70710678118654752f));
}

__global__ __launch_bounds__(256) void dct_fused(
    const float* __restrict__ x,
    const float* __restrict__ noise,
    const float* __restrict__ qmat,
    const float* __restrict__ qmw,
    const float* __restrict__ w1, const float* __restrict__ b1,
    const float* __restrict__ w2, const float* __restrict__ b2,
    const float* __restrict__ w3, const float* __restrict__ b3,
    float* __restrict__ lo, float* __restrict__ hi) {
  __shared__ float Qs[64];
  __shared__ float s_h1[16], s_h2[16], s_nr[18], s_c[16], s_qw[16];

  const int tid = threadIdx.x;

  // ---- tiny MLP -> Q, recomputed per workgroup (overlapped, fp32) ----
  if (tid < 16) {
    float v = noise[0] * w1[tid] + b1[tid];
    s_h1[tid] = gelu_exact(v);
    s_qw[tid] = qmw[tid];
  }
  __syncthreads();
  if (tid < 16) {
    float v = b2[tid];
#pragma unroll
    for (int i = 0; i < 16; ++i) v = fmaf(s_h1[i], w2[i * 16 + tid], v);
    s_h2[tid] = gelu_exact(v);
  }
  __syncthreads();
  if (tid < 18) {
    float v = b3[tid];
#pragma unroll
    for (int i = 0; i < 16; ++i) v = fmaf(s_h2[i], w3[i * 18 + tid], v);
    s_nr[tid] = v;
  }
  __syncthreads();
  if (tid < 16) {
    float mx = s_qw[0];
#pragma unroll
    for (int i = 1; i < 16; ++i) mx = fmaxf(mx, s_qw[i]);
    float s = 0.0f;
#pragma unroll
    for (int i = 0; i < 16; ++i) s += expf(s_qw[i] - mx);
    float e = expf(s_qw[tid] - mx);
    s_c[tid] = (e / s * s_nr[0] + s_nr[1]) * s_nr[2 + tid];
  }
  __syncthreads();
  if (tid < 64) {
    float q = 0.0f;
#pragma unroll
    for (int i = 0; i < 16; ++i) q = fmaf(s_c[i], qmat[i * 64 + tid], q);
    Qs[tid] = q;
  }
  __syncthreads();

  // ---- main: one thread per 8x8 block, X kept in regs for high = X-low ----
  const int gid = blockIdx.x * 256 + tid;
  // image n = gid>>6, band = (gid>>3)&7, block-col = gid&7 ; W = 64 floats/row
  const int base = ((gid >> 6) << 12) | (((gid >> 3) & 7) << 9) | ((gid & 7) << 3);
  const float* px = x + base;

  float X[8][8];
#pragma unroll
  for (int r = 0; r < 8; ++r) {
    const f4 a = __builtin_nontemporal_load(reinterpret_cast<const f4*>(px + r * 64));
    const f4 b = __builtin_nontemporal_load(reinterpret_cast<const f4*>(px + r * 64 + 4));
    X[r][0] = a.x; X[r][1] = a.y; X[r][2] = a.z; X[r][3] = a.w;
    X[r][4] = b.x; X[r][5] = b.y; X[r][6] = b.z; X[r][7] = b.w;
  }

  float U[8][8];
  // Stage 1: U = X * C^T   (U[r][j] = sum_l X[r][l] * C[j][l])
#pragma unroll
  for (int r = 0; r < 8; ++r) {
#pragma unroll
    for (int j = 0; j < 8; ++j) {
      float s = X[r][0] * cc(j, 0);
#pragma unroll
      for (int l = 1; l < 8; ++l) s = fmaf(X[r][l], cc(j, l), s);
      U[r][j] = s;
    }
  }
  // Stage 2: D = C * U, fused mask: U[i][j] = D[i][j] * Q[i][j]
#pragma unroll
  for (int j = 0; j < 8; ++j) {
    float t[8];
#pragma unroll
    for (int i = 0; i < 8; ++i) {
      float s = cc(i, 0) * U[0][j];
#pragma unroll
      for (int k = 1; k < 8; ++k) s = fmaf(cc(i, k), U[k][j], s);
      t[i] = s;
    }
#pragma unroll
    for (int i = 0; i < 8; ++i) U[i][j] = t[i] * Qs[i * 8 + j];
  }
  // Stage 3: V = M * C   (V[r][j] = sum_k M[r][k] * C[k][j])
#pragma unroll
  for (int r = 0; r < 8; ++r) {
    float t[8];
#pragma unroll
    for (int j = 0; j < 8; ++j) {
      float s = U[r][0] * cc(0, j);
#pragma unroll
      for (int k = 1; k < 8; ++k) s = fmaf(U[r][k], cc(k, j), s);
      t[j] = s;
    }
#pragma unroll
    for (int j = 0; j < 8; ++j) U[r][j] = t[j];
  }
  // Stage 4: low = C^T * V   (low[i][j] = sum_k C[k][i] * V[k][j])
#pragma unroll
  for (int j = 0; j < 8; ++j) {
    float t[8];
#pragma unroll
    for (int i = 0; i < 8; ++i) {
      float s = cc(0, i) * U[0][j];
#pragma unroll
      for (int k = 1; k < 8; ++k) s = fmaf(cc(k, i), U[k][j], s);
      t[i] = s;
    }
#pragma unroll
    for (int i = 0; i < 8; ++i) U[i][j] = t[i];
  }

  float* plo = lo + base;
  float* phi = hi + base;
#pragma unroll
  for (int r = 0; r < 8; ++r) {
    f4 a = {U[r][0], U[r][1], U[r][2], U[r][3]};
    f4 b = {U[r][4], U[r][5], U[r][6], U[r][7]};
    __builtin_nontemporal_store(a, reinterpret_cast<f4*>(plo + r * 64));
    __builtin_nontemporal_store(b, reinterpret_cast<f4*>(plo + r * 64 + 4));
    f4 c = {X[r][0] - U[r][0], X[r][1] - U[r][1],
            X[r][2] - U[r][2], X[r][3] - U[r][3]};
    f4 d = {X[r][4] - U[r][4], X[r][5] - U[r][5],
            X[r][6] - U[r][6], X[r][7] - U[r][7]};
    __builtin_nontemporal_store(c, reinterpret_cast<f4*>(phi + r * 64));
    __builtin_nontemporal_store(d, reinterpret_cast<f4*>(phi + r * 64 + 4));
  }
}

extern "C" void kernel_launch(void* const* d_in, const int* in_sizes, int n_in,
                              void* d_out, int out_size, void* d_ws, size_t ws_size,
                              hipStream_t stream) {
  const float* x   = (const float*)d_in[0];
  const float* nl  = (const float*)d_in[1];
  const float* qm  = (const float*)d_in[2];
  const float* qmw = (const float*)d_in[3];
  const float* w1  = (const float*)d_in[4];
  const float* b1  = (const float*)d_in[5];
  const float* w2  = (const float*)d_in[6];
  const float* b2  = (const float*)d_in[7];
  const float* w3  = (const float*)d_in[8];
  const float* b3  = (const float*)d_in[9];

  const int n_elem = in_sizes[0];          // 33554432
  float* lo = (float*)d_out;
  float* hi = lo + n_elem;

  const int n_blocks8 = n_elem >> 6;       // 524288 8x8 blocks
  const int grid = n_blocks8 >> 8;         // 2048 workgroups of 256
  dct_fused<<<grid, 256, 0, stream>>>(x, nl, qm, qmw, w1, b1, w2, b2, w3, b3,
                                      lo, hi);
}

// Round 3
// 430.062 us; speedup vs baseline: 1.0839x; 1.0420x over previous
//
#include <hip/hip_runtime.h>
#include <math.h>

// ---------------------------------------------------------------------------
// LearnableDCTNet.
//   low  = C^T ((C X C^T) * Q) C ;  high = X - low
// C compile-time constant (exact DCT-II; differs from reference's
// truncated-pi basis by <2e-7/entry -> ~1e-5 at output; threshold 1.08e-1).
// Round-3 changes vs round 2:
//  * MLP -> Q moved back to a tiny setup kernel (d_ws); main kernel has ONE
//    barrier (Q -> LDS) instead of a 5-barrier transcendental preamble
//    serialized on every workgroup round.
//  * Stores are NOT nontemporal: NT partial-line (16B of each 32B) stores
//    caused 1.44x HBM write amplification (WRITE_SIZE 386MB vs 268MB ideal).
//    Regular stores let L2 assemble full lines. Loads stay NT (use-once).
// ---------------------------------------------------------------------------

typedef float f4 __attribute__((ext_vector_type(4)));

// cos(k*pi/16), k = 0..31 (full period)
__host__ __device__ constexpr float cc(int i, int j) {
  constexpr double COS16[32] = {
     1.0,
     0.98078528040323043,
     0.92387953251128674,
     0.83146961230254524,
     0.70710678118654752,
     0.55557023301960222,
     0.38268343236508977,
     0.19509032201612827,
     0.0,
    -0.19509032201612827,
    -0.38268343236508977,
    -0.55557023301960222,
    -0.70710678118654752,
    -0.83146961230254524,
    -0.92387953251128674,
    -0.98078528040323043,
    -1.0,
    -0.98078528040323043,
    -0.92387953251128674,
    -0.83146961230254524,
    -0.70710678118654752,
    -0.55557023301960222,
    -0.38268343236508977,
    -0.19509032201612827,
     0.0,
     0.19509032201612827,
     0.38268343236508977,
     0.55557023301960222,
     0.70710678118654752,
     0.83146961230254524,
     0.92387953251128674,
     0.98078528040323043,
  };
  // C[0][j] = sqrt(1/8); C[i][j] = 0.5 * cos(pi*i*(2j+1)/16)
  return (i == 0) ? 0.35355339059327373f
                  : (float)(0.5 * COS16[(i * (2 * j + 1)) % 32]);
}

// ---------------------------------------------------------------------------
// Setup: noise MLP (exact-erf GELU) in fp64 -> Q (64 floats) in d_ws.
// ---------------------------------------------------------------------------
__global__ void setup_q(const float* __restrict__ noise,
                        const float* __restrict__ qmat,
                        const float* __restrict__ qmw,
                        const float* __restrict__ w1, const float* __restrict__ b1,
                        const float* __restrict__ w2, const float* __restrict__ b2,
                        const float* __restrict__ w3, const float* __restrict__ b3,
                        float* __restrict__ qout) {
  __shared__ double coeff[16];
  if (threadIdx.x == 0) {
    const double inv_sqrt2 = 0.70710678118654752;
    double h1[16], h2[16], nr[18];
    double nl = (double)noise[0];
    for (int j = 0; j < 16; ++j) {
      double v = nl * (double)w1[j] + (double)b1[j];
      h1[j] = 0.5 * v * (1.0 + erf(v * inv_sqrt2));
    }
    for (int j = 0; j < 16; ++j) {
      double v = (double)b2[j];
      for (int i = 0; i < 16; ++i) v += h1[i] * (double)w2[i * 16 + j];
      h2[j] = 0.5 * v * (1.0 + erf(v * inv_sqrt2));
    }
    for (int j = 0; j < 18; ++j) {
      double v = (double)b3[j];
      for (int i = 0; i < 16; ++i) v += h2[i] * (double)w3[i * 18 + j];
      nr[j] = v;
    }
    double mx = (double)qmw[0];
    for (int i = 1; i < 16; ++i) mx = fmax(mx, (double)qmw[i]);
    double e[16], s = 0.0;
    for (int i = 0; i < 16; ++i) { e[i] = exp((double)qmw[i] - mx); s += e[i]; }
    for (int i = 0; i < 16; ++i)
      coeff[i] = (e[i] / s * nr[0] + nr[1]) * nr[2 + i];
  }
  __syncthreads();
  const int t = threadIdx.x;  // 64 threads, one Q entry each
  double q = 0.0;
  for (int i = 0; i < 16; ++i) q += coeff[i] * (double)qmat[i * 64 + t];
  qout[t] = (float)q;
}

// ---------------------------------------------------------------------------
// Main: one thread per 8x8 block. X kept in 64 regs for high = X - low.
// One barrier (Q -> LDS). NT loads, regular stores.
// ---------------------------------------------------------------------------
__global__ __launch_bounds__(256) void dct_main(const float* __restrict__ x,
                                                const float* __restrict__ qg,
                                                float* __restrict__ lo,
                                                float* __restrict__ hi) {
  __shared__ float Qs[64];
  const int tid = threadIdx.x;
  if (tid < 64) Qs[tid] = qg[tid];
  __syncthreads();

  const int gid = blockIdx.x * 256 + tid;
  // image n = gid>>6, band = (gid>>3)&7, block-col = gid&7 ; W = 64 floats/row
  const int base = ((gid >> 6) << 12) | (((gid >> 3) & 7) << 9) | ((gid & 7) << 3);
  const float* px = x + base;

  float X[8][8];
#pragma unroll
  for (int r = 0; r < 8; ++r) {
    const f4 a = __builtin_nontemporal_load(reinterpret_cast<const f4*>(px + r * 64));
    const f4 b = __builtin_nontemporal_load(reinterpret_cast<const f4*>(px + r * 64 + 4));
    X[r][0] = a.x; X[r][1] = a.y; X[r][2] = a.z; X[r][3] = a.w;
    X[r][4] = b.x; X[r][5] = b.y; X[r][6] = b.z; X[r][7] = b.w;
  }

  float U[8][8];
  // Stage 1: U = X * C^T   (U[r][j] = sum_l X[r][l] * C[j][l])
#pragma unroll
  for (int r = 0; r < 8; ++r) {
#pragma unroll
    for (int j = 0; j < 8; ++j) {
      float s = X[r][0] * cc(j, 0);
#pragma unroll
      for (int l = 1; l < 8; ++l) s = fmaf(X[r][l], cc(j, l), s);
      U[r][j] = s;
    }
  }
  // Stage 2: D = C * U, fused mask: U[i][j] = D[i][j] * Q[i][j]
#pragma unroll
  for (int j = 0; j < 8; ++j) {
    float t[8];
#pragma unroll
    for (int i = 0; i < 8; ++i) {
      float s = cc(i, 0) * U[0][j];
#pragma unroll
      for (int k = 1; k < 8; ++k) s = fmaf(cc(i, k), U[k][j], s);
      t[i] = s;
    }
#pragma unroll
    for (int i = 0; i < 8; ++i) U[i][j] = t[i] * Qs[i * 8 + j];
  }
  // Stage 3: V = M * C   (V[r][j] = sum_k M[r][k] * C[k][j])
#pragma unroll
  for (int r = 0; r < 8; ++r) {
    float t[8];
#pragma unroll
    for (int j = 0; j < 8; ++j) {
      float s = U[r][0] * cc(0, j);
#pragma unroll
      for (int k = 1; k < 8; ++k) s = fmaf(U[r][k], cc(k, j), s);
      t[j] = s;
    }
#pragma unroll
    for (int j = 0; j < 8; ++j) U[r][j] = t[j];
  }
  // Stage 4: low = C^T * V   (low[i][j] = sum_k C[k][i] * V[k][j])
#pragma unroll
  for (int j = 0; j < 8; ++j) {
    float t[8];
#pragma unroll
    for (int i = 0; i < 8; ++i) {
      float s = cc(0, i) * U[0][j];
#pragma unroll
      for (int k = 1; k < 8; ++k) s = fmaf(cc(k, i), U[k][j], s);
      t[i] = s;
    }
#pragma unroll
    for (int i = 0; i < 8; ++i) U[i][j] = t[i];
  }

  float* plo = lo + base;
  float* phi = hi + base;
#pragma unroll
  for (int r = 0; r < 8; ++r) {
    f4 a = {U[r][0], U[r][1], U[r][2], U[r][3]};
    f4 b = {U[r][4], U[r][5], U[r][6], U[r][7]};
    *reinterpret_cast<f4*>(plo + r * 64)     = a;
    *reinterpret_cast<f4*>(plo + r * 64 + 4) = b;
    f4 c = {X[r][0] - U[r][0], X[r][1] - U[r][1],
            X[r][2] - U[r][2], X[r][3] - U[r][3]};
    f4 d = {X[r][4] - U[r][4], X[r][5] - U[r][5],
            X[r][6] - U[r][6], X[r][7] - U[r][7]};
    *reinterpret_cast<f4*>(phi + r * 64)     = c;
    *reinterpret_cast<f4*>(phi + r * 64 + 4) = d;
  }
}

extern "C" void kernel_launch(void* const* d_in, const int* in_sizes, int n_in,
                              void* d_out, int out_size, void* d_ws, size_t ws_size,
                              hipStream_t stream) {
  const float* x   = (const float*)d_in[0];
  const float* nl  = (const float*)d_in[1];
  const float* qm  = (const float*)d_in[2];
  const float* qmw = (const float*)d_in[3];
  const float* w1  = (const float*)d_in[4];
  const float* b1  = (const float*)d_in[5];
  const float* w2  = (const float*)d_in[6];
  const float* b2  = (const float*)d_in[7];
  const float* w3  = (const float*)d_in[8];
  const float* b3  = (const float*)d_in[9];

  const int n_elem = in_sizes[0];          // 33554432
  float* lo = (float*)d_out;
  float* hi = lo + n_elem;
  float* q  = (float*)d_ws;                // 64 floats

  setup_q<<<1, 64, 0, stream>>>(nl, qm, qmw, w1, b1, w2, b2, w3, b3, q);

  const int n_blocks8 = n_elem >> 6;       // 524288 8x8 blocks
  const int grid = n_blocks8 >> 8;         // 2048 workgroups of 256
  dct_main<<<grid, 256, 0, stream>>>(x, q, lo, hi);
}